// Round 9
// baseline (978.318 us; speedup 1.0000x reference)
//
#include <hip/hip_runtime.h>
#include <hip/hip_bf16.h>
#include <math.h>

// F_IN=256, H=4, C=32, H*C=128; NEG_SLOPE_ATT=0.2, NEG_SLOPE_ACT=0.01, EPS=1e-5
// bias skipped: batch-stat BatchNorm subtracts it exactly.
//
// R1..R7: CSR agg, 4exp/edge, MFMA GEMM w/ fused att scores, bucket sort,
//         no-max softmax, dword-pair h layout.
// R8: bucket_csr_k + agg_csr_k FUSED into bucket_agg_k: one block per
//     64-dst bucket, 64x128 fp32 LDS tile + LDS denominators, ds_add
//     accumulation from unsorted bucket pairs. Kills the exact CSR build,
//     ssrc/off arrays, and the pairs re-read. Self-loops = 64 virtual
//     leading edges. hist1 grid 256->64 (4x fewer flush atomics).

typedef __attribute__((ext_vector_type(8))) short bf8_t;   // 8 bf16 in 4 VGPRs
typedef __attribute__((ext_vector_type(4))) float f4_t;    // MFMA accumulator

__device__ inline unsigned short f2bf(float f) {  // RNE fp32->bf16
  unsigned u = __float_as_uint(f);
  u += 0x7fff + ((u >> 16) & 1);
  return (unsigned short)(u >> 16);
}
__device__ inline float lrelu02(float v) { return v > 0.f ? v : 0.2f * v; }

#define LSTRIDE 264  // 256 + 8 bf16 pad

// ------- MFMA GEMM + fused att scores -------
// hb2[node][j] (dword) = ( bf16 h[node][j] , bf16 h[node][j+64] )
__global__ __launch_bounds__(256) void gemm_mfma(const float* __restrict__ x,
                                                 const float* __restrict__ w,
                                                 const float* __restrict__ att_s,
                                                 const float* __restrict__ att_d,
                                                 unsigned* __restrict__ hb2,
                                                 float* __restrict__ a_s,
                                                 float* __restrict__ a_d,
                                                 int n, int ntiles) {
  __shared__ unsigned short wsl[128 * LSTRIDE];  // 67.6 KB
  __shared__ unsigned short xsl[64 * LSTRIDE];   // 33.8 KB
  int tid = threadIdx.x;
  int lane = tid & 63;
  int wid = tid >> 6;
  int quad = lane >> 4;
  int l15 = lane & 15;

  float attS[8], attD[8];
#pragma unroll
  for (int t = 0; t < 8; t++) {
    attS[t] = att_s[t * 16 + l15];
    attD[t] = att_d[t * 16 + l15];
  }

  // stage W once: 128 rows x 64 float4 = 8192 f4, 32/thread
#pragma unroll 4
  for (int i = 0; i < 32; i++) {
    int idx = tid + i * 256;
    int row = idx >> 6;
    int f4 = idx & 63;
    float4 v = *(const float4*)&w[(size_t)row * 256 + f4 * 4];
    unsigned p01 = f2bf(v.x) | ((unsigned)f2bf(v.y) << 16);
    unsigned p23 = f2bf(v.z) | ((unsigned)f2bf(v.w) << 16);
    *(uint2*)&wsl[row * LSTRIDE + f4 * 4] = make_uint2(p01, p23);
  }

  float4 pre[16];
  int tile = blockIdx.x;
  if (tile < ntiles) {
#pragma unroll
    for (int i = 0; i < 16; i++) {
      int idx = tid + i * 256;
      int row = idx >> 6, f4 = idx & 63;
      int grow = tile * 64 + row;
      pre[i] = (grow < n) ? *(const float4*)&x[(size_t)grow * 256 + f4 * 4]
                          : make_float4(0.f, 0.f, 0.f, 0.f);
    }
  }

  for (; tile < ntiles; tile += gridDim.x) {
    __syncthreads();
#pragma unroll
    for (int i = 0; i < 16; i++) {
      int idx = tid + i * 256;
      int row = idx >> 6, f4 = idx & 63;
      unsigned p01 = f2bf(pre[i].x) | ((unsigned)f2bf(pre[i].y) << 16);
      unsigned p23 = f2bf(pre[i].z) | ((unsigned)f2bf(pre[i].w) << 16);
      *(uint2*)&xsl[row * LSTRIDE + f4 * 4] = make_uint2(p01, p23);
    }
    __syncthreads();

    int nxt = tile + gridDim.x;
    if (nxt < ntiles) {
#pragma unroll
      for (int i = 0; i < 16; i++) {
        int idx = tid + i * 256;
        int row = idx >> 6, f4 = idx & 63;
        int grow = nxt * 64 + row;
        pre[i] = (grow < n) ? *(const float4*)&x[(size_t)grow * 256 + f4 * 4]
                            : make_float4(0.f, 0.f, 0.f, 0.f);
      }
    }

    f4_t acc[8];
#pragma unroll
    for (int t = 0; t < 8; t++) acc[t] = (f4_t){0.f, 0.f, 0.f, 0.f};
    const unsigned short* arow = &xsl[(wid * 16 + l15) * LSTRIDE];
#pragma unroll
    for (int ks = 0; ks < 8; ks++) {
      bf8_t af = *(const bf8_t*)&arow[ks * 32 + quad * 8];
#pragma unroll
      for (int t = 0; t < 8; t++) {
        bf8_t bf = *(const bf8_t*)&wsl[(t * 16 + l15) * LSTRIDE + ks * 32 + quad * 8];
        acc[t] = __builtin_amdgcn_mfma_f32_16x16x32_bf16(af, bf, acc[t], 0, 0, 0);
      }
    }

    // C/D layout: col = lane&15 (-> t*16+l15), row = quad*4 + reg  [m89-verified]
    int growb = tile * 64 + wid * 16 + quad * 4;
#pragma unroll
    for (int r = 0; r < 4; r++) {
      int grow = growb + r;
      bool ok = grow < n;
      if (ok) {
        unsigned* orow = &hb2[(size_t)grow * 64];
#pragma unroll
        for (int t = 0; t < 4; t++)
          orow[t * 16 + l15] =
              (unsigned)f2bf(acc[t][r]) | ((unsigned)f2bf(acc[t + 4][r]) << 16);
      }
      float sp[4], dp[4];
#pragma unroll
      for (int hh = 0; hh < 4; hh++) {
        sp[hh] = acc[2 * hh][r] * attS[2 * hh] + acc[2 * hh + 1][r] * attS[2 * hh + 1];
        dp[hh] = acc[2 * hh][r] * attD[2 * hh] + acc[2 * hh + 1][r] * attD[2 * hh + 1];
      }
#pragma unroll
      for (int m = 1; m < 16; m <<= 1) {
#pragma unroll
        for (int hh = 0; hh < 4; hh++) {
          sp[hh] += __shfl_xor(sp[hh], m, 64);
          dp[hh] += __shfl_xor(dp[hh], m, 64);
        }
      }
      float vs = l15 == 0 ? sp[0] : l15 == 1 ? sp[1] : l15 == 2 ? sp[2] : sp[3];
      float vd = l15 == 0 ? dp[0] : l15 == 1 ? dp[1] : l15 == 2 ? dp[2] : dp[3];
      if (ok && l15 < 4) {
        a_s[grow * 4 + l15] = vs;
        a_d[grow * 4 + l15] = vd;
      }
    }
  }
}

// ---------------- bucket sort: hist + scan + aggregated scatter ----------------
__global__ __launch_bounds__(256) void hist1_k(const int* __restrict__ dst,
                                               int* __restrict__ bcnt, int E, int nb) {
  __shared__ int lh[1024];
  for (int t = threadIdx.x; t < nb; t += 256) lh[t] = 0;
  __syncthreads();
  for (int i = blockIdx.x * 256 + threadIdx.x; i < E; i += gridDim.x * 256)
    atomicAdd(&lh[dst[i] >> 6], 1);
  __syncthreads();
  for (int t = threadIdx.x; t < nb; t += 256) {
    int v = lh[t];
    if (v) atomicAdd(&bcnt[t], v);
  }
}

__global__ __launch_bounds__(1024) void scan_buckets_k(const int* __restrict__ bcnt,
                                                       int* __restrict__ pbase,
                                                       int* __restrict__ pcur,
                                                       int nb) {
  __shared__ int sa[1024];
  int t = threadIdx.x;
  int c = (t < nb) ? bcnt[t] : 0;
  sa[t] = c;
  __syncthreads();
  for (int o = 1; o < 1024; o <<= 1) {
    int xa = (t >= o) ? sa[t - o] : 0;
    __syncthreads();
    sa[t] += xa;
    __syncthreads();
  }
  if (t < nb) {
    pbase[t] = sa[t] - c;
    pcur[t] = sa[t] - c;
  }
}

__global__ __launch_bounds__(1024) void pair_scatter2_k(const int* __restrict__ src,
                                                        const int* __restrict__ dst,
                                                        int* __restrict__ pcur,
                                                        unsigned* __restrict__ pairs,
                                                        int E, int nb) {
  __shared__ int cnt[1024];
  int t = threadIdx.x;
  int chunk = (E + gridDim.x - 1) / gridDim.x;
  int lo = blockIdx.x * chunk;
  int hi = min(E, lo + chunk);
  for (int i = t; i < nb; i += 1024) cnt[i] = 0;
  __syncthreads();
  for (int i = lo + t; i < hi; i += 1024) atomicAdd(&cnt[dst[i] >> 6], 1);
  __syncthreads();
  for (int i = t; i < nb; i += 1024) {
    int c = cnt[i];
    cnt[i] = c ? atomicAdd(&pcur[i], c) : 0;  // reserve dense run
  }
  __syncthreads();
  for (int i = lo + t; i < hi; i += 1024) {
    int d = dst[i];
    int pos = atomicAdd(&cnt[d >> 6], 1);
    pairs[pos] = (unsigned)src[i] | ((unsigned)(d & 63) << 26);
  }
}

// -------- fused softmax + aggregation, one block per 64-dst bucket --------
// LDS 64x128 fp32 tile + per-dst denominators; unsorted bucket pairs;
// self-loops = dcnt virtual leading edges. out written densely at the end.
__global__ __launch_bounds__(256) void bucket_agg_k(const unsigned* __restrict__ pairs,
                                                    const int* __restrict__ bcnt,
                                                    const int* __restrict__ pbase,
                                                    const float* __restrict__ a_s,
                                                    const float* __restrict__ a_d,
                                                    const unsigned* __restrict__ hb2,
                                                    float* __restrict__ out, int n) {
  __shared__ float tile[64 * 128];  // 32 KB
  __shared__ float lsum[64 * 4];    // per-dst, per-head denominators
  __shared__ float adl[64 * 4];     // bucket's a_d rows
  __shared__ float pst[256 * 4];    // staged weights (p0,p2,p1,p3)
  __shared__ int sl[256], dll[256];

  int tid = threadIdx.x;
  int wid = tid >> 6;
  int lane = tid & 63;
  int half = lane >> 5;
  int b = blockIdx.x;
  int d0 = b << 6;
  int dcnt = min(64, n - d0);
  int cnt = bcnt[b];
  int pstart = pbase[b];

  // init: zero tile + lsum, preload a_d for the bucket
  for (int i = tid; i < 64 * 128; i += 256) tile[i] = 0.f;
  if (tid < 256) {
    if (tid < 64 * 4) lsum[tid] = 0.f;
    adl[tid] = (tid < dcnt * 4) ? a_d[d0 * 4 + tid] : 0.f;
  }
  __syncthreads();

  int m = cnt + dcnt;  // virtual self edges first
  for (int base = 0; base < m; base += 256) {
    int c2 = min(256, m - base);
    int e = base + tid;
    if (e < m) {
      int s, dl;
      if (e < dcnt) { dl = e; s = d0 + e; }
      else {
        unsigned u = pairs[pstart + e - dcnt];
        dl = (int)(u >> 26);
        s = (int)(u & 0x03FFFFFFu);
      }
      float4 as4 = *(const float4*)&a_s[s * 4];
      float4 ad4 = *(const float4*)&adl[dl * 4];
      float p0 = __expf(lrelu02(as4.x + ad4.x));
      float p1 = __expf(lrelu02(as4.y + ad4.y));
      float p2 = __expf(lrelu02(as4.z + ad4.z));
      float p3 = __expf(lrelu02(as4.w + ad4.w));
      atomicAdd(&lsum[dl * 4 + 0], p0);
      atomicAdd(&lsum[dl * 4 + 1], p1);
      atomicAdd(&lsum[dl * 4 + 2], p2);
      atomicAdd(&lsum[dl * 4 + 3], p3);
      sl[tid] = s;
      dll[tid] = dl;
      *(float4*)&pst[tid * 4] = make_float4(p0, p2, p1, p3);
    }
    __syncthreads();

    int k = wid;
    for (; k + 4 < c2; k += 8) {
      int sA = __builtin_amdgcn_readfirstlane(sl[k]);
      int dA = __builtin_amdgcn_readfirstlane(dll[k]);
      int sB = __builtin_amdgcn_readfirstlane(sl[k + 4]);
      int dB = __builtin_amdgcn_readfirstlane(dll[k + 4]);
      unsigned gA = hb2[(size_t)sA * 64 + lane];
      unsigned gB = hb2[(size_t)sB * 64 + lane];
      float2 pA = *(const float2*)&pst[k * 4 + half * 2];
      float2 pB = *(const float2*)&pst[(k + 4) * 4 + half * 2];
      atomicAdd(&tile[dA * 128 + lane], pA.x * __uint_as_float(gA << 16));
      atomicAdd(&tile[dA * 128 + 64 + lane], pA.y * __uint_as_float(gA & 0xffff0000u));
      atomicAdd(&tile[dB * 128 + lane], pB.x * __uint_as_float(gB << 16));
      atomicAdd(&tile[dB * 128 + 64 + lane], pB.y * __uint_as_float(gB & 0xffff0000u));
    }
    if (k < c2) {
      int sA = __builtin_amdgcn_readfirstlane(sl[k]);
      int dA = __builtin_amdgcn_readfirstlane(dll[k]);
      unsigned gA = hb2[(size_t)sA * 64 + lane];
      float2 pA = *(const float2*)&pst[k * 4 + half * 2];
      atomicAdd(&tile[dA * 128 + lane], pA.x * __uint_as_float(gA << 16));
      atomicAdd(&tile[dA * 128 + 64 + lane], pA.y * __uint_as_float(gA & 0xffff0000u));
    }
    __syncthreads();
  }

  // epilogue: normalize + dense coalesced out write
  int j = tid & 127;
  int rh = tid >> 7;  // 0/1 -> rows [0,32) / [32,64)
  int hsel = j >> 5;
#pragma unroll 4
  for (int r = rh * 32; r < rh * 32 + 32; r++) {
    if (r < dcnt) {
      float inv = 1.0f / lsum[r * 4 + hsel];
      out[(size_t)(d0 + r) * 128 + j] = tile[r * 128 + j] * inv;
    }
  }
}

// -------------------------- BatchNorm --------------------------
__global__ __launch_bounds__(256) void bn_stats_k(const float* __restrict__ out,
                                                  float* __restrict__ sums,
                                                  float* __restrict__ sumsq, int n) {
  int j = threadIdx.x & 127;
  int strm = blockIdx.x * 2 + (threadIdx.x >> 7);
  int stride = gridDim.x * 2;
  float s = 0.f, s2 = 0.f;
  for (int r = strm; r < n; r += stride) {
    float v = out[(size_t)r * 128 + j];
    s += v;
    s2 += v * v;
  }
  atomicAdd(&sums[j], s);
  atomicAdd(&sumsq[j], s2);
}

__global__ void bn_coef_k(const float* __restrict__ sums,
                          const float* __restrict__ sumsq,
                          const float* __restrict__ gamma,
                          const float* __restrict__ beta,
                          float* __restrict__ scale, float* __restrict__ shift,
                          float inv_n) {
  int j = threadIdx.x;
  float mu = sums[j] * inv_n;
  float var = sumsq[j] * inv_n - mu * mu;
  float rstd = 1.0f / sqrtf(var + 1e-5f);
  float g = gamma[j] * rstd;
  scale[j] = g;
  shift[j] = beta[j] - mu * g;
}

__global__ __launch_bounds__(256) void bn_apply_k(float* __restrict__ out,
                                                  const float* __restrict__ scale,
                                                  const float* __restrict__ shift,
                                                  int n4) {
  int i = blockIdx.x * 256 + threadIdx.x;
  if (i >= n4) return;
  float4 v = ((float4*)out)[i];
  int j = (i & 31) << 2;
  const float4 sc = *(const float4*)&scale[j];
  const float4 sh = *(const float4*)&shift[j];
  v.x = fmaf(v.x, sc.x, sh.x);
  v.y = fmaf(v.y, sc.y, sh.y);
  v.z = fmaf(v.z, sc.z, sh.z);
  v.w = fmaf(v.w, sc.w, sh.w);
  v.x = v.x > 0.f ? v.x : 0.01f * v.x;
  v.y = v.y > 0.f ? v.y : 0.01f * v.y;
  v.z = v.z > 0.f ? v.z : 0.01f * v.z;
  v.w = v.w > 0.f ? v.w : 0.01f * v.w;
  ((float4*)out)[i] = v;
}

static inline char* align16(char* p) {
  return (char*)(((uintptr_t)p + 15) & ~(uintptr_t)15);
}

extern "C" void kernel_launch(void* const* d_in, const int* in_sizes, int n_in,
                              void* d_out, int out_size, void* d_ws, size_t ws_size,
                              hipStream_t stream) {
  const float* x     = (const float*)d_in[0];
  const int*   ei    = (const int*)d_in[1];
  const float* W     = (const float*)d_in[2];
  const float* att_s = (const float*)d_in[3];
  const float* att_d = (const float*)d_in[4];
  // d_in[5] = bias: cancels under batch-stat BN
  const float* gamma = (const float*)d_in[6];
  const float* beta  = (const float*)d_in[7];

  int n = in_sizes[0] / 256;
  int E = in_sizes[1] / 2;
  const int* src = ei;
  const int* dstp = ei + E;
  float* out = (float*)d_out;

  int NBUCK = (n + 63) >> 6;   // <= 1024 for n <= 65536
  int ntiles = (n + 63) / 64;

  char* p = (char*)d_ws;
  unsigned* hb2 = (unsigned*)p; p = align16(p + (size_t)n * 64 * 4);
  float* a_s   = (float*)p; p = align16(p + (size_t)n * 4 * 4);
  float* a_d   = (float*)p; p = align16(p + (size_t)n * 4 * 4);
  float* sums  = (float*)p; p = align16(p + 128 * 4);
  float* sumsq = (float*)p; p = align16(p + 128 * 4);
  float* scale = (float*)p; p = align16(p + 128 * 4);
  float* shift = (float*)p; p = align16(p + 128 * 4);
  int* bcnt    = (int*)p;   p = align16(p + (size_t)NBUCK * 4);
  int* pbase   = (int*)p;   p = align16(p + (size_t)NBUCK * 4);
  int* pcur    = (int*)p;   p = align16(p + (size_t)NBUCK * 4);
  unsigned* pairs = (unsigned*)p; p = align16(p + (size_t)E * 4);

  hipMemsetAsync(sums, 0, 2 * 128 * 4, stream);  // sums+sumsq contiguous
  hipMemsetAsync(bcnt, 0, (size_t)NBUCK * 4, stream);

  gemm_mfma<<<256, 256, 0, stream>>>(x, W, att_s, att_d, hb2, a_s, a_d, n, ntiles);

  hist1_k<<<64, 256, 0, stream>>>(dstp, bcnt, E, NBUCK);
  scan_buckets_k<<<1, 1024, 0, stream>>>(bcnt, pbase, pcur, NBUCK);
  pair_scatter2_k<<<64, 1024, 0, stream>>>(src, dstp, pcur, pairs, E, NBUCK);

  bucket_agg_k<<<NBUCK, 256, 0, stream>>>(pairs, bcnt, pbase, a_s, a_d, hb2, out, n);

  bn_stats_k<<<256, 256, 0, stream>>>(out, sums, sumsq, n);
  bn_coef_k<<<1, 128, 0, stream>>>(sums, sumsq, gamma, beta, scale, shift, 1.0f / n);
  bn_apply_k<<<(n * 32 + 255) / 256, 256, 0, stream>>>(out, scale, shift, n * 32);
}

// Round 10
// 234.432 us; speedup vs baseline: 4.1731x; 4.1731x over previous
//
#include <hip/hip_runtime.h>
#include <hip/hip_bf16.h>
#include <math.h>

// F_IN=256, H=4, C=32, H*C=128; NEG_SLOPE_ATT=0.2, NEG_SLOPE_ACT=0.01, EPS=1e-5
// bias skipped: batch-stat BatchNorm subtracts it exactly.
//
// R1..R7: CSR agg (one wave/dst), 4exp/edge, MFMA GEMM + fused att scores,
//         bucket sort w/ block-aggregated reservation, no-max softmax,
//         dword-pair h layout.
// R8: bucket-fused agg REGRESSED 774us (latency serialization, 2.6% VALU).
// R9: revert to wave-per-dst agg; + half-wave edge pairs (dwordx2 gather,
//     ~half VALU/edge); + fixed-stride bucket regions (PSTRIDE) kill
//     hist1+scan dispatches; + bn_coef folded into bn_apply; single memset.

typedef __attribute__((ext_vector_type(8))) short bf8_t;   // 8 bf16 in 4 VGPRs
typedef __attribute__((ext_vector_type(4))) float f4_t;    // MFMA accumulator

__device__ inline unsigned short f2bf(float f) {  // RNE fp32->bf16
  unsigned u = __float_as_uint(f);
  u += 0x7fff + ((u >> 16) & 1);
  return (unsigned short)(u >> 16);
}
__device__ inline float lrelu02(float v) { return v > 0.f ? v : 0.2f * v; }
__device__ inline float bflo(unsigned g) { return __uint_as_float(g << 16); }
__device__ inline float bfhi(unsigned g) { return __uint_as_float(g & 0xffff0000u); }

#define LSTRIDE 264   // 256 + 8 bf16 pad
#define PSTRIDE 2048  // per-bucket pairs region (max bucket ~1130 = 32 sigma)
#define SSTRIDE 2112  // PSTRIDE + 64 self-loops

// ------- MFMA GEMM + fused att scores -------
// hb2[node][j] (dword) = ( bf16 h[node][j] , bf16 h[node][j+64] )
__global__ __launch_bounds__(256) void gemm_mfma(const float* __restrict__ x,
                                                 const float* __restrict__ w,
                                                 const float* __restrict__ att_s,
                                                 const float* __restrict__ att_d,
                                                 unsigned* __restrict__ hb2,
                                                 float* __restrict__ a_s,
                                                 float* __restrict__ a_d,
                                                 int n, int ntiles) {
  __shared__ unsigned short wsl[128 * LSTRIDE];  // 67.6 KB
  __shared__ unsigned short xsl[64 * LSTRIDE];   // 33.8 KB
  int tid = threadIdx.x;
  int lane = tid & 63;
  int wid = tid >> 6;
  int quad = lane >> 4;
  int l15 = lane & 15;

  float attS[8], attD[8];
#pragma unroll
  for (int t = 0; t < 8; t++) {
    attS[t] = att_s[t * 16 + l15];
    attD[t] = att_d[t * 16 + l15];
  }

  // stage W once: 128 rows x 64 float4 = 8192 f4, 32/thread
#pragma unroll 4
  for (int i = 0; i < 32; i++) {
    int idx = tid + i * 256;
    int row = idx >> 6;
    int f4 = idx & 63;
    float4 v = *(const float4*)&w[(size_t)row * 256 + f4 * 4];
    unsigned p01 = f2bf(v.x) | ((unsigned)f2bf(v.y) << 16);
    unsigned p23 = f2bf(v.z) | ((unsigned)f2bf(v.w) << 16);
    *(uint2*)&wsl[row * LSTRIDE + f4 * 4] = make_uint2(p01, p23);
  }

  float4 pre[16];
  int tile = blockIdx.x;
  if (tile < ntiles) {
#pragma unroll
    for (int i = 0; i < 16; i++) {
      int idx = tid + i * 256;
      int row = idx >> 6, f4 = idx & 63;
      int grow = tile * 64 + row;
      pre[i] = (grow < n) ? *(const float4*)&x[(size_t)grow * 256 + f4 * 4]
                          : make_float4(0.f, 0.f, 0.f, 0.f);
    }
  }

  for (; tile < ntiles; tile += gridDim.x) {
    __syncthreads();
#pragma unroll
    for (int i = 0; i < 16; i++) {
      int idx = tid + i * 256;
      int row = idx >> 6, f4 = idx & 63;
      unsigned p01 = f2bf(pre[i].x) | ((unsigned)f2bf(pre[i].y) << 16);
      unsigned p23 = f2bf(pre[i].z) | ((unsigned)f2bf(pre[i].w) << 16);
      *(uint2*)&xsl[row * LSTRIDE + f4 * 4] = make_uint2(p01, p23);
    }
    __syncthreads();

    int nxt = tile + gridDim.x;
    if (nxt < ntiles) {
#pragma unroll
      for (int i = 0; i < 16; i++) {
        int idx = tid + i * 256;
        int row = idx >> 6, f4 = idx & 63;
        int grow = nxt * 64 + row;
        pre[i] = (grow < n) ? *(const float4*)&x[(size_t)grow * 256 + f4 * 4]
                            : make_float4(0.f, 0.f, 0.f, 0.f);
      }
    }

    f4_t acc[8];
#pragma unroll
    for (int t = 0; t < 8; t++) acc[t] = (f4_t){0.f, 0.f, 0.f, 0.f};
    const unsigned short* arow = &xsl[(wid * 16 + l15) * LSTRIDE];
#pragma unroll
    for (int ks = 0; ks < 8; ks++) {
      bf8_t af = *(const bf8_t*)&arow[ks * 32 + quad * 8];
#pragma unroll
      for (int t = 0; t < 8; t++) {
        bf8_t bf = *(const bf8_t*)&wsl[(t * 16 + l15) * LSTRIDE + ks * 32 + quad * 8];
        acc[t] = __builtin_amdgcn_mfma_f32_16x16x32_bf16(af, bf, acc[t], 0, 0, 0);
      }
    }

    // C/D layout: col = lane&15 (-> t*16+l15), row = quad*4 + reg  [m89-verified]
    int growb = tile * 64 + wid * 16 + quad * 4;
#pragma unroll
    for (int r = 0; r < 4; r++) {
      int grow = growb + r;
      bool ok = grow < n;
      if (ok) {
        unsigned* orow = &hb2[(size_t)grow * 64];
#pragma unroll
        for (int t = 0; t < 4; t++)
          orow[t * 16 + l15] =
              (unsigned)f2bf(acc[t][r]) | ((unsigned)f2bf(acc[t + 4][r]) << 16);
      }
      float sp[4], dp[4];
#pragma unroll
      for (int hh = 0; hh < 4; hh++) {
        sp[hh] = acc[2 * hh][r] * attS[2 * hh] + acc[2 * hh + 1][r] * attS[2 * hh + 1];
        dp[hh] = acc[2 * hh][r] * attD[2 * hh] + acc[2 * hh + 1][r] * attD[2 * hh + 1];
      }
#pragma unroll
      for (int mm = 1; mm < 16; mm <<= 1) {
#pragma unroll
        for (int hh = 0; hh < 4; hh++) {
          sp[hh] += __shfl_xor(sp[hh], mm, 64);
          dp[hh] += __shfl_xor(dp[hh], mm, 64);
        }
      }
      float vs = l15 == 0 ? sp[0] : l15 == 1 ? sp[1] : l15 == 2 ? sp[2] : sp[3];
      float vd = l15 == 0 ? dp[0] : l15 == 1 ? dp[1] : l15 == 2 ? dp[2] : dp[3];
      if (ok && l15 < 4) {
        a_s[grow * 4 + l15] = vs;
        a_d[grow * 4 + l15] = vd;
      }
    }
  }
}

// --- scatter into FIXED per-bucket regions; bcnt doubles as cursor (no scan) ---
__global__ __launch_bounds__(1024) void pair_scatter3_k(const int* __restrict__ src,
                                                        const int* __restrict__ dst,
                                                        int* __restrict__ bcnt,
                                                        unsigned* __restrict__ pairs,
                                                        int E, int nb) {
  __shared__ int cnt[1024];
  int t = threadIdx.x;
  int chunk = (E + gridDim.x - 1) / gridDim.x;
  int lo = blockIdx.x * chunk;
  int hi = min(E, lo + chunk);
  for (int i = t; i < nb; i += 1024) cnt[i] = 0;
  __syncthreads();
  for (int i = lo + t; i < hi; i += 1024) atomicAdd(&cnt[dst[i] >> 6], 1);
  __syncthreads();
  for (int i = t; i < nb; i += 1024) {
    int c = cnt[i];
    cnt[i] = c ? atomicAdd(&bcnt[i], c) : 0;  // reserve dense run in bucket region
  }
  __syncthreads();
  for (int i = lo + t; i < hi; i += 1024) {
    int d = dst[i];
    int b = d >> 6;
    int pos = atomicAdd(&cnt[b], 1);
    if (pos < PSTRIDE)
      pairs[(size_t)b * PSTRIDE + pos] = (unsigned)src[i] | ((unsigned)(d & 63) << 26);
  }
}

// --- one block per bucket -> per-dst segments in strided ssrc (+dlen) ---
__global__ __launch_bounds__(256) void bucket_csr_k(const unsigned* __restrict__ pairs,
                                                    const int* __restrict__ bcnt,
                                                    int* __restrict__ off,
                                                    int* __restrict__ dlen,
                                                    int* __restrict__ ssrc, int n) {
  __shared__ int hist[64], lofs[64], curs[64];
  int b = blockIdx.x;
  int t = threadIdx.x;
  int d0 = b << 6;
  int dcnt = min(64, n - d0);
  int cnt = min(bcnt[b], PSTRIDE);
  size_t pstart = (size_t)b * PSTRIDE;
  int ob = b * SSTRIDE;
  if (t < 64) hist[t] = (t < dcnt) ? 1 : 0;  // self-loop seeds count
  __syncthreads();
  for (int i = t; i < cnt; i += 256) atomicAdd(&hist[pairs[pstart + i] >> 26], 1);
  __syncthreads();
  if (t == 0) {
    int acc = 0;
    for (int k = 0; k < 64; k++) { lofs[k] = acc; acc += hist[k]; }
  }
  __syncthreads();
  if (t < dcnt) {
    int lo = lofs[t];
    off[d0 + t] = ob + lo;
    dlen[d0 + t] = hist[t];
    curs[t] = lo + 1;          // slot 0 = self-loop
    ssrc[ob + lo] = d0 + t;    // self-loop entry
  }
  __syncthreads();
  for (int i = t; i < cnt; i += 256) {
    unsigned u = pairs[pstart + i];
    int dl = u >> 26;
    int pos = ob + atomicAdd(&curs[dl], 1);
    ssrc[pos] = (int)(u & 0x03FFFFFFu);
  }
}

// -------- aggregation: one wave per dst, half-wave edge pairs --------
// lane = 32*half + m: half picks edge of the pair, m picks 4 cols
// {2m, 2m+1, 2m+64, 2m+65}; per lane one dwordx2 load per pair-step.
__global__ __launch_bounds__(256) void agg_csr_k(const int* __restrict__ off,
                                                 const int* __restrict__ dlen,
                                                 const int* __restrict__ ssrc,
                                                 const float* __restrict__ a_s,
                                                 const float* __restrict__ a_d,
                                                 const unsigned* __restrict__ hb2,
                                                 float* __restrict__ out, int n) {
  __shared__ float lp[4][64 * 4];
  __shared__ int lsrc[4][64];
  int tid = threadIdx.x;
  int wid = tid >> 6;
  int lane = tid & 63;
  int d = blockIdx.x * 4 + wid;
  if (d >= n) return;  // no block-wide barriers below: safe
  int start = off[d];
  int end = start + dlen[d];
  float4 ad4 = *(const float4*)&a_d[d * 4];
  int half = lane >> 5;
  int m = lane & 31;
  int hsel = m >> 4;  // head pair: heads hsel, hsel+2

  float l0 = 0.f, l1 = 0.f, l2 = 0.f, l3 = 0.f;
  float a00 = 0.f, a01 = 0.f, a10 = 0.f, a11 = 0.f;
  for (int base = start; base < end; base += 64) {
    int cnt = min(64, end - base);
    int j = base + lane;
    if (j < end) {
      int s = ssrc[j];
      float4 as4 = *(const float4*)&a_s[s * 4];
      float p0 = __expf(lrelu02(as4.x + ad4.x));
      float p1 = __expf(lrelu02(as4.y + ad4.y));
      float p2 = __expf(lrelu02(as4.z + ad4.z));
      float p3 = __expf(lrelu02(as4.w + ad4.w));
      l0 += p0; l1 += p1; l2 += p2; l3 += p3;
      lsrc[wid][lane] = s;
      *(float4*)&lp[wid][lane * 4] = make_float4(p0, p2, p1, p3);
    }
    int k = 0;
    for (; k + 8 <= cnt; k += 8) {  // 4 pair-steps, 4 loads in flight
      int e0 = k + half, e1 = k + 2 + half, e2 = k + 4 + half, e3 = k + 6 + half;
      int s0 = lsrc[wid][e0], s1 = lsrc[wid][e1];
      int s2 = lsrc[wid][e2], s3 = lsrc[wid][e3];
      uint2 g0 = *(const uint2*)&hb2[(size_t)s0 * 64 + m * 2];
      uint2 g1 = *(const uint2*)&hb2[(size_t)s1 * 64 + m * 2];
      uint2 g2 = *(const uint2*)&hb2[(size_t)s2 * 64 + m * 2];
      uint2 g3 = *(const uint2*)&hb2[(size_t)s3 * 64 + m * 2];
      float2 p0 = *(const float2*)&lp[wid][e0 * 4 + hsel * 2];
      float2 p1 = *(const float2*)&lp[wid][e1 * 4 + hsel * 2];
      float2 p2 = *(const float2*)&lp[wid][e2 * 4 + hsel * 2];
      float2 p3 = *(const float2*)&lp[wid][e3 * 4 + hsel * 2];
      a00 = fmaf(p0.x, bflo(g0.x), a00); a10 = fmaf(p0.y, bfhi(g0.x), a10);
      a01 = fmaf(p0.x, bflo(g0.y), a01); a11 = fmaf(p0.y, bfhi(g0.y), a11);
      a00 = fmaf(p1.x, bflo(g1.x), a00); a10 = fmaf(p1.y, bfhi(g1.x), a10);
      a01 = fmaf(p1.x, bflo(g1.y), a01); a11 = fmaf(p1.y, bfhi(g1.y), a11);
      a00 = fmaf(p2.x, bflo(g2.x), a00); a10 = fmaf(p2.y, bfhi(g2.x), a10);
      a01 = fmaf(p2.x, bflo(g2.y), a01); a11 = fmaf(p2.y, bfhi(g2.y), a11);
      a00 = fmaf(p3.x, bflo(g3.x), a00); a10 = fmaf(p3.y, bfhi(g3.x), a10);
      a01 = fmaf(p3.x, bflo(g3.y), a01); a11 = fmaf(p3.y, bfhi(g3.y), a11);
    }
    for (; k + 2 <= cnt; k += 2) {
      int e0 = k + half;
      int s0 = lsrc[wid][e0];
      uint2 g0 = *(const uint2*)&hb2[(size_t)s0 * 64 + m * 2];
      float2 p0 = *(const float2*)&lp[wid][e0 * 4 + hsel * 2];
      a00 = fmaf(p0.x, bflo(g0.x), a00); a10 = fmaf(p0.y, bfhi(g0.x), a10);
      a01 = fmaf(p0.x, bflo(g0.y), a01); a11 = fmaf(p0.y, bfhi(g0.y), a11);
    }
    if (k < cnt && half == 0) {  // odd remainder: half0 lanes only
      int s0 = lsrc[wid][k];
      uint2 g0 = *(const uint2*)&hb2[(size_t)s0 * 64 + m * 2];
      float2 p0 = *(const float2*)&lp[wid][k * 4 + hsel * 2];
      a00 = fmaf(p0.x, bflo(g0.x), a00); a10 = fmaf(p0.y, bfhi(g0.x), a10);
      a01 = fmaf(p0.x, bflo(g0.y), a01); a11 = fmaf(p0.y, bfhi(g0.y), a11);
    }
  }

  // merge the two halves' accumulators (same columns, different edges)
  a00 += __shfl_xor(a00, 32, 64);
  a01 += __shfl_xor(a01, 32, 64);
  a10 += __shfl_xor(a10, 32, 64);
  a11 += __shfl_xor(a11, 32, 64);
#pragma unroll
  for (int o = 1; o < 64; o <<= 1) {
    l0 += __shfl_xor(l0, o, 64);
    l1 += __shfl_xor(l1, o, 64);
    l2 += __shfl_xor(l2, o, 64);
    l3 += __shfl_xor(l3, o, 64);
  }
  float il0 = 1.0f / (hsel ? l1 : l0);
  float il1 = 1.0f / (hsel ? l3 : l2);
  if (half == 0) {
    *(float2*)&out[(size_t)d * 128 + 2 * m] = make_float2(a00 * il0, a01 * il0);
    *(float2*)&out[(size_t)d * 128 + 64 + 2 * m] = make_float2(a10 * il1, a11 * il1);
  }
}

// -------------------------- BatchNorm --------------------------
__global__ __launch_bounds__(256) void bn_stats_k(const float* __restrict__ out,
                                                  float* __restrict__ sums,
                                                  float* __restrict__ sumsq, int n) {
  int j = threadIdx.x & 127;
  int strm = blockIdx.x * 2 + (threadIdx.x >> 7);
  int stride = gridDim.x * 2;
  float s = 0.f, s2 = 0.f;
  for (int r = strm; r < n; r += stride) {
    float v = out[(size_t)r * 128 + j];
    s += v;
    s2 += v * v;
  }
  atomicAdd(&sums[j], s);
  atomicAdd(&sumsq[j], s2);
}

// normalize + LeakyReLU(0.01); BN coefs computed per-block from sums/sumsq
__global__ __launch_bounds__(256) void bn_apply_k(float* __restrict__ out,
                                                  const float* __restrict__ sums,
                                                  const float* __restrict__ sumsq,
                                                  const float* __restrict__ gamma,
                                                  const float* __restrict__ beta,
                                                  float inv_n, int n4) {
  __shared__ float sc[128], sh[128];
  int tid = threadIdx.x;
  if (tid < 128) {
    float mu = sums[tid] * inv_n;
    float var = sumsq[tid] * inv_n - mu * mu;
    float rstd = 1.0f / sqrtf(var + 1e-5f);
    float g = gamma[tid] * rstd;
    sc[tid] = g;
    sh[tid] = beta[tid] - mu * g;
  }
  __syncthreads();
  int i = blockIdx.x * 256 + tid;
  if (i >= n4) return;
  float4 v = ((float4*)out)[i];
  int j = (i & 31) << 2;
  const float4 scv = *(const float4*)&sc[j];
  const float4 shv = *(const float4*)&sh[j];
  v.x = fmaf(v.x, scv.x, shv.x);
  v.y = fmaf(v.y, scv.y, shv.y);
  v.z = fmaf(v.z, scv.z, shv.z);
  v.w = fmaf(v.w, scv.w, shv.w);
  v.x = v.x > 0.f ? v.x : 0.01f * v.x;
  v.y = v.y > 0.f ? v.y : 0.01f * v.y;
  v.z = v.z > 0.f ? v.z : 0.01f * v.z;
  v.w = v.w > 0.f ? v.w : 0.01f * v.w;
  ((float4*)out)[i] = v;
}

static inline char* align16(char* p) {
  return (char*)(((uintptr_t)p + 15) & ~(uintptr_t)15);
}

extern "C" void kernel_launch(void* const* d_in, const int* in_sizes, int n_in,
                              void* d_out, int out_size, void* d_ws, size_t ws_size,
                              hipStream_t stream) {
  const float* x     = (const float*)d_in[0];
  const int*   ei    = (const int*)d_in[1];
  const float* W     = (const float*)d_in[2];
  const float* att_s = (const float*)d_in[3];
  const float* att_d = (const float*)d_in[4];
  // d_in[5] = bias: cancels under batch-stat BN
  const float* gamma = (const float*)d_in[6];
  const float* beta  = (const float*)d_in[7];

  int n = in_sizes[0] / 256;
  int E = in_sizes[1] / 2;
  const int* src = ei;
  const int* dstp = ei + E;
  float* out = (float*)d_out;

  int NBUCK = (n + 63) >> 6;   // <= 1024 for n <= 65536
  int ntiles = (n + 63) / 64;

  char* p = (char*)d_ws;
  unsigned* hb2 = (unsigned*)p; p = align16(p + (size_t)n * 64 * 4);
  float* a_s   = (float*)p; p = align16(p + (size_t)n * 4 * 4);
  float* a_d   = (float*)p; p = align16(p + (size_t)n * 4 * 4);
  // sums | sumsq | bcnt contiguous -> ONE memset
  float* sums  = (float*)p;
  float* sumsq = sums + 128;
  int*   bcnt  = (int*)(sums + 256);
  p = align16((char*)(bcnt + NBUCK));
  int* off     = (int*)p;   p = align16(p + (size_t)n * 4);
  int* dlen    = (int*)p;   p = align16(p + (size_t)n * 4);
  int* ssrc    = (int*)p;   p = align16(p + (size_t)NBUCK * SSTRIDE * 4);
  unsigned* pairs = (unsigned*)p; p = align16(p + (size_t)NBUCK * PSTRIDE * 4);

  hipMemsetAsync(sums, 0, (256 + (size_t)NBUCK) * 4, stream);

  gemm_mfma<<<256, 256, 0, stream>>>(x, W, att_s, att_d, hb2, a_s, a_d, n, ntiles);

  pair_scatter3_k<<<64, 1024, 0, stream>>>(src, dstp, bcnt, pairs, E, NBUCK);
  bucket_csr_k<<<NBUCK, 256, 0, stream>>>(pairs, bcnt, off, dlen, ssrc, n);

  agg_csr_k<<<(n + 3) / 4, 256, 0, stream>>>(off, dlen, ssrc, a_s, a_d, hb2, out, n);

  bn_stats_k<<<256, 256, 0, stream>>>(out, sums, sumsq, n);
  bn_apply_k<<<(n * 32 + 255) / 256, 256, 0, stream>>>(out, sums, sumsq, gamma, beta,
                                                       1.0f / n, n * 32);
}